// Round 2
// baseline (4163.780 us; speedup 1.0000x reference)
//
#include <hip/hip_runtime.h>

typedef __bf16 bf16x8 __attribute__((ext_vector_type(8)));
typedef float  f32x4  __attribute__((ext_vector_type(4)));

#define AGENT __HIP_MEMORY_SCOPE_AGENT

// ---------------------------------------------------------------------------
// Kernel 1: xproj = x @ Wih^T + bih, written fp32 directly into d_out's
// states region (kernel 2 reads it there and overwrites in place with h).
// Grid (512, 8): 64x64 output tile per block. 16x16x32 bf16 MFMA.
// ---------------------------------------------------------------------------
__global__ __launch_bounds__(256) void xproj_gemm_kernel(
    const float* __restrict__ x, const float* __restrict__ Wih,
    const float* __restrict__ bih, float* __restrict__ out)
{
    __shared__ __bf16 Ash[64][72];   // +8 bf16 pad: row stride 144B, 2-way banks
    __shared__ __bf16 Bsh[64][72];

    const int tid  = threadIdx.x;
    const int wave = tid >> 6, lane = tid & 63;
    const int col  = lane & 15, kq = lane >> 4;
    const int bt0  = blockIdx.x * 64;
    const int h0   = blockIdx.y * 64;

    f32x4 acc[4];
#pragma unroll
    for (int nt = 0; nt < 4; ++nt) acc[nt] = (f32x4){0.f, 0.f, 0.f, 0.f};

    const int r  = tid >> 2;         // staging row 0..63
    const int cb = (tid & 3) * 16;   // staging col base

    for (int k0 = 0; k0 < 512; k0 += 64) {
        const float* ax = x   + (size_t)(bt0 + r) * 512 + k0 + cb;
        const float* bx = Wih + (size_t)(h0  + r) * 512 + k0 + cb;
#pragma unroll
        for (int j = 0; j < 4; ++j) {
            const float4 av = ((const float4*)ax)[j];
            const float4 bv = ((const float4*)bx)[j];
            const int c = cb + 4 * j;
            Ash[r][c+0]=(__bf16)av.x; Ash[r][c+1]=(__bf16)av.y;
            Ash[r][c+2]=(__bf16)av.z; Ash[r][c+3]=(__bf16)av.w;
            Bsh[r][c+0]=(__bf16)bv.x; Bsh[r][c+1]=(__bf16)bv.y;
            Bsh[r][c+2]=(__bf16)bv.z; Bsh[r][c+3]=(__bf16)bv.w;
        }
        __syncthreads();
#pragma unroll
        for (int kt = 0; kt < 2; ++kt) {
            bf16x8 a = *(const bf16x8*)&Ash[wave * 16 + col][kt * 32 + kq * 8];
#pragma unroll
            for (int nt = 0; nt < 4; ++nt) {
                bf16x8 bb = *(const bf16x8*)&Bsh[nt * 16 + col][kt * 32 + kq * 8];
                acc[nt] = __builtin_amdgcn_mfma_f32_16x16x32_bf16(a, bb, acc[nt], 0, 0, 0);
            }
        }
        __syncthreads();
    }
    // C/D layout: col = lane&15, row = (lane>>4)*4 + reg
#pragma unroll
    for (int nt = 0; nt < 4; ++nt) {
        const float bv = bih[h0 + nt * 16 + col];
#pragma unroll
        for (int reg = 0; reg < 4; ++reg) {
            const int m = bt0 + wave * 16 + kq * 4 + reg;
            out[(size_t)m * 512 + h0 + nt * 16 + col] = acc[nt][reg] + bv;
        }
    }
}

// ---------------------------------------------------------------------------
// Kernel 2: the recurrence. 128 blocks = 32 batches x P=4 h_out slices.
// Each block holds Whh[p*128:(p+1)*128, :] as bf16 MFMA B-fragments in VGPRs
// (weight-stationary). Per step: 32 MFMAs (A = h_read broadcast to all 16
// rows -> every lane's acc holds y[col]), tanh, fp32 exchange of the 4
// slices through LLC with device-scope flags, Lagrange combine for next
// h_read. Block-id swizzle puts a group's 4 blocks on the same XCD.
// ---------------------------------------------------------------------------
__global__ __launch_bounds__(256) void lagrange_rnn_kernel(
    const float* __restrict__ Whh, const float* __restrict__ bhh,
    const float* __restrict__ kern, float* __restrict__ out,
    float* __restrict__ exch, unsigned* __restrict__ flags)
{
    const int id   = blockIdx.x;                 // 0..127
    const int b    = (id & 7) + ((id >> 5) << 3);// batch 0..31 (group)
    const int p    = (id >> 3) & 3;              // slice member 0..3
    const int tid  = threadIdx.x;
    const int wave = tid >> 6, lane = tid & 63;
    const int col  = lane & 15, kq = lane >> 4;

    __shared__ float  hist[4][512];   // circular h history, fp32
    __shared__ __bf16 hread[512];     // h_read(t) as MFMA A operand

    for (int i = tid; i < 2048; i += 256) ((float*)hist)[i] = 0.f;
    for (int i = tid; i < 512;  i += 256) hread[i] = (__bf16)0.f;

    // --- load weight fragments (once): wave w owns houts [p*128+w*32, +32)
    const int hA = p * 128 + wave * 32 + col;   // N-tile 2w
    const int hB = hA + 16;                     // N-tile 2w+1
    bf16x8 wf0[16], wf1[16];
#pragma unroll
    for (int kt = 0; kt < 16; ++kt) {
        const float* s0 = Whh + (size_t)hA * 512 + kt * 32 + kq * 8;
        const float* s1 = Whh + (size_t)hB * 512 + kt * 32 + kq * 8;
        const float4 a0 = *(const float4*)s0, a1 = *(const float4*)(s0 + 4);
        const float4 b0 = *(const float4*)s1, b1 = *(const float4*)(s1 + 4);
        bf16x8 w;
        w[0]=(__bf16)a0.x; w[1]=(__bf16)a0.y; w[2]=(__bf16)a0.z; w[3]=(__bf16)a0.w;
        w[4]=(__bf16)a1.x; w[5]=(__bf16)a1.y; w[6]=(__bf16)a1.z; w[7]=(__bf16)a1.w;
        wf0[kt] = w;
        w[0]=(__bf16)b0.x; w[1]=(__bf16)b0.y; w[2]=(__bf16)b0.z; w[3]=(__bf16)b0.w;
        w[4]=(__bf16)b1.x; w[5]=(__bf16)b1.y; w[6]=(__bf16)b1.z; w[7]=(__bf16)b1.w;
        wf1[kt] = w;
    }
    const float k0 = kern[0], k1 = kern[1], k2 = kern[2], k3 = kern[3];
    const float bA = bhh[hA], bB = bhh[hB];
    float* stA = out + (size_t)b * 1024 * 512 + hA;   // states[b][t][hA], +t*512
    const int i0 = tid * 2;
    unsigned* myflag = flags + (b * 4 + p) * 16;
    __syncthreads();

    for (int t = 0; t < 1024; ++t) {
        // prefetch xp (lives in out until we overwrite it with h)
        const float xA = stA[(size_t)t * 512];
        const float xB = stA[(size_t)t * 512 + 16];

        // --- A: y = h_read . W_slice^T   (A rows all identical -> acc[i]==y[col])
        f32x4 acc0 = (f32x4){0.f,0.f,0.f,0.f}, acc1 = (f32x4){0.f,0.f,0.f,0.f};
#pragma unroll
        for (int kt = 0; kt < 16; ++kt) {
            bf16x8 a = *(const bf16x8*)&hread[kt * 32 + kq * 8];
            acc0 = __builtin_amdgcn_mfma_f32_16x16x32_bf16(a, wf0[kt], acc0, 0, 0, 0);
            acc1 = __builtin_amdgcn_mfma_f32_16x16x32_bf16(a, wf1[kt], acc1, 0, 0, 0);
        }

        // --- E1: partial Lagrange combine from h(t-1..t-3) (rows != t&3)
        const int rm1 = (t + 3) & 3, rm2 = (t + 2) & 3, rm3 = (t + 1) & 3, rt = t & 3;
        const float pp0 = k1 * hist[rm1][i0]     + k2 * hist[rm2][i0]     + k3 * hist[rm3][i0];
        const float pp1 = k1 * hist[rm1][i0 + 1] + k2 * hist[rm2][i0 + 1] + k3 * hist[rm3][i0 + 1];

        // --- B: tanh + write states (in place over xp) + own slice into hist
        if (lane < 16) {
            const float hAv = tanhf(xA + acc0[0] + bA);
            const float hBv = tanhf(xB + acc1[0] + bB);
            stA[(size_t)t * 512]      = hAv;
            stA[(size_t)t * 512 + 16] = hBv;
            hist[rt][hA] = hAv;
            hist[rt][hB] = hBv;
        }
        __syncthreads();

        // --- C/D: exchange among the 4 slice blocks (wave 0 only)
        if (wave == 0) {
            const float v0 = hist[rt][p * 128 + lane * 2];
            const float v1 = hist[rt][p * 128 + lane * 2 + 1];
            float* eb = exch + (size_t)(((b * 2 + (t & 1)) * 4 + p) << 7);
            __hip_atomic_store(eb + lane * 2,     v0, __ATOMIC_RELAXED, AGENT);
            __hip_atomic_store(eb + lane * 2 + 1, v1, __ATOMIC_RELAXED, AGENT);
            __builtin_amdgcn_fence(__ATOMIC_RELEASE, "agent");
            if (lane == 0)
                __hip_atomic_store(myflag, (unsigned)(t + 1), __ATOMIC_RELAXED, AGENT);
            if (lane < 4 && lane != p) {
                while (__hip_atomic_load(flags + (b * 4 + lane) * 16,
                                         __ATOMIC_RELAXED, AGENT) < (unsigned)(t + 1)) { }
            }
            __builtin_amdgcn_fence(__ATOMIC_ACQUIRE, "agent");
#pragma unroll
            for (int q = 0; q < 4; ++q) {
                if (q == p) continue;
                const float* pb = exch + (size_t)(((b * 2 + (t & 1)) * 4 + q) << 7);
                const float u0 = __hip_atomic_load(pb + lane * 2,     __ATOMIC_RELAXED, AGENT);
                const float u1 = __hip_atomic_load(pb + lane * 2 + 1, __ATOMIC_RELAXED, AGENT);
                hist[rt][q * 128 + lane * 2]     = u0;
                hist[rt][q * 128 + lane * 2 + 1] = u1;
            }
        }
        __syncthreads();

        // --- E2: finish h_read(t+1) = pp + k0*h(t), round to bf16 for MFMA
        hread[i0]     = (__bf16)(pp0 + k0 * hist[rt][i0]);
        hread[i0 + 1] = (__bf16)(pp1 + k0 * hist[rt][i0 + 1]);
        __syncthreads();
    }

    // final state output: h(1023) sits in hist[1023 & 3 == 3]
    float* out2 = out + (size_t)32 * 1024 * 512 + (size_t)b * 512;
    out2[i0]     = hist[3][i0];
    out2[i0 + 1] = hist[3][i0 + 1];
}

// ---------------------------------------------------------------------------
extern "C" void kernel_launch(void* const* d_in, const int* in_sizes, int n_in,
                              void* d_out, int out_size, void* d_ws, size_t ws_size,
                              hipStream_t stream) {
    const float* x    = (const float*)d_in[0];   // [32,1024,512]
    const float* Wih  = (const float*)d_in[1];   // [512,512]
    const float* Whh  = (const float*)d_in[2];   // [512,512]
    const float* bih  = (const float*)d_in[3];   // [512]
    const float* bhh  = (const float*)d_in[4];   // [512]
    const float* kern = (const float*)d_in[5];   // [4]
    float* out = (float*)d_out;

    // workspace: exchange buffer (32 batches x 2 slots x 4 slices x 128 fp32)
    // then flags (32x4, padded to 64B each). ~140 KB total.
    float*    exch  = (float*)d_ws;
    unsigned* flags = (unsigned*)((char*)d_ws + 32 * 2 * 4 * 128 * sizeof(float));

    (void)hipMemsetAsync(flags, 0, 32 * 4 * 16 * sizeof(unsigned), stream);

    dim3 g1(512, 8, 1);   // (BT/64, H/64)
    xproj_gemm_kernel<<<g1, 256, 0, stream>>>(x, Wih, bih, out);
    lagrange_rnn_kernel<<<128, 256, 0, stream>>>(Whh, bhh, kern, out, exch, flags);
}

// Round 3
// 2057.417 us; speedup vs baseline: 2.0238x; 2.0238x over previous
//
#include <hip/hip_runtime.h>

typedef __bf16 bf16x8 __attribute__((ext_vector_type(8)));
typedef float  f32x4  __attribute__((ext_vector_type(4)));
typedef unsigned long long u64;

#define AGENT __HIP_MEMORY_SCOPE_AGENT

// ---------------------------------------------------------------------------
// Kernel 1: xproj = x @ Wih^T + bih, written fp32 directly into d_out's
// states region (kernel 2 reads it there and overwrites in place with h).
// Grid (512, 8): 64x64 output tile per block. 16x16x32 bf16 MFMA.
// ---------------------------------------------------------------------------
__global__ __launch_bounds__(256) void xproj_gemm_kernel(
    const float* __restrict__ x, const float* __restrict__ Wih,
    const float* __restrict__ bih, float* __restrict__ out)
{
    __shared__ __bf16 Ash[64][72];   // +8 bf16 pad
    __shared__ __bf16 Bsh[64][72];

    const int tid  = threadIdx.x;
    const int wave = tid >> 6, lane = tid & 63;
    const int col  = lane & 15, kq = lane >> 4;
    const int bt0  = blockIdx.x * 64;
    const int h0   = blockIdx.y * 64;

    f32x4 acc[4];
#pragma unroll
    for (int nt = 0; nt < 4; ++nt) acc[nt] = (f32x4){0.f, 0.f, 0.f, 0.f};

    const int r  = tid >> 2;         // staging row 0..63
    const int cb = (tid & 3) * 16;   // staging col base

    for (int k0 = 0; k0 < 512; k0 += 64) {
        const float* ax = x   + (size_t)(bt0 + r) * 512 + k0 + cb;
        const float* bx = Wih + (size_t)(h0  + r) * 512 + k0 + cb;
#pragma unroll
        for (int j = 0; j < 4; ++j) {
            const float4 av = ((const float4*)ax)[j];
            const float4 bv = ((const float4*)bx)[j];
            const int c = cb + 4 * j;
            Ash[r][c+0]=(__bf16)av.x; Ash[r][c+1]=(__bf16)av.y;
            Ash[r][c+2]=(__bf16)av.z; Ash[r][c+3]=(__bf16)av.w;
            Bsh[r][c+0]=(__bf16)bv.x; Bsh[r][c+1]=(__bf16)bv.y;
            Bsh[r][c+2]=(__bf16)bv.z; Bsh[r][c+3]=(__bf16)bv.w;
        }
        __syncthreads();
#pragma unroll
        for (int kt = 0; kt < 2; ++kt) {
            bf16x8 a = *(const bf16x8*)&Ash[wave * 16 + col][kt * 32 + kq * 8];
#pragma unroll
            for (int nt = 0; nt < 4; ++nt) {
                bf16x8 bb = *(const bf16x8*)&Bsh[nt * 16 + col][kt * 32 + kq * 8];
                acc[nt] = __builtin_amdgcn_mfma_f32_16x16x32_bf16(a, bb, acc[nt], 0, 0, 0);
            }
        }
        __syncthreads();
    }
    // C/D layout: col = lane&15, row = (lane>>4)*4 + reg
#pragma unroll
    for (int nt = 0; nt < 4; ++nt) {
        const float bv = bih[h0 + nt * 16 + col];
#pragma unroll
        for (int reg = 0; reg < 4; ++reg) {
            const int m = bt0 + wave * 16 + kq * 4 + reg;
            out[(size_t)m * 512 + h0 + nt * 16 + col] = acc[nt][reg] + bv;
        }
    }
}

// ---------------------------------------------------------------------------
// Kernel 2: the recurrence. 128 blocks = 32 batches x P=4 h_out slices,
// weight-stationary Whh slices in VGPR/AGPR MFMA B-fragments.
// Exchange: fence-free tagged-u64 mailboxes in LLC. Each value travels as
// (tag<<32 | fp32 bits) via relaxed agent-scope atomics; the tag (t+1)
// self-validates, so no release/acquire fences (no buffer_inv, no vmcnt(0)
// drain) are needed. Parity double-buffer prevents t/t+2 overwrite races.
// Poison-proof: polls use exact tag match (0xAAAAAAAA never matches).
// ---------------------------------------------------------------------------
__global__ __launch_bounds__(256) void lagrange_rnn_kernel(
    const float* __restrict__ Whh, const float* __restrict__ bhh,
    const float* __restrict__ kern, float* __restrict__ out,
    u64* __restrict__ mbox)
{
    const int id   = blockIdx.x;                 // 0..127
    const int b    = (id & 7) + ((id >> 5) << 3);// batch 0..31 (group on one XCD)
    const int p    = (id >> 3) & 3;              // slice member 0..3
    const int tid  = threadIdx.x;
    const int wave = tid >> 6, lane = tid & 63;
    const int col  = lane & 15, kq = lane >> 4;

    __shared__ float  hist[4][512];   // circular h history, fp32
    __shared__ __bf16 hread[512];     // h_read(t) as MFMA A operand

    for (int i = tid; i < 2048; i += 256) ((float*)hist)[i] = 0.f;
    for (int i = tid; i < 512;  i += 256) hread[i] = (__bf16)0.f;

    // --- weight fragments (once): wave w owns houts [p*128+w*32, +32)
    const int hA = p * 128 + wave * 32 + col;   // N-tile 2w
    const int hB = hA + 16;                     // N-tile 2w+1
    bf16x8 wf0[16], wf1[16];
#pragma unroll
    for (int kt = 0; kt < 16; ++kt) {
        const float* s0 = Whh + (size_t)hA * 512 + kt * 32 + kq * 8;
        const float* s1 = Whh + (size_t)hB * 512 + kt * 32 + kq * 8;
        const float4 a0 = *(const float4*)s0, a1 = *(const float4*)(s0 + 4);
        const float4 b0 = *(const float4*)s1, b1 = *(const float4*)(s1 + 4);
        bf16x8 w;
        w[0]=(__bf16)a0.x; w[1]=(__bf16)a0.y; w[2]=(__bf16)a0.z; w[3]=(__bf16)a0.w;
        w[4]=(__bf16)a1.x; w[5]=(__bf16)a1.y; w[6]=(__bf16)a1.z; w[7]=(__bf16)a1.w;
        wf0[kt] = w;
        w[0]=(__bf16)b0.x; w[1]=(__bf16)b0.y; w[2]=(__bf16)b0.z; w[3]=(__bf16)b0.w;
        w[4]=(__bf16)b1.x; w[5]=(__bf16)b1.y; w[6]=(__bf16)b1.z; w[7]=(__bf16)b1.w;
        wf1[kt] = w;
    }
    const float k0 = kern[0], k1 = kern[1], k2 = kern[2], k3 = kern[3];
    const float bA = bhh[hA], bB = bhh[hB];
    float* stA = out + (size_t)b * 1024 * 512 + hA;   // states[b][t][hA], +t*512
    const int i0 = tid * 2;
    const int peer = (p + wave) & 3;                  // waves 1..3 poll this peer
    __syncthreads();

    for (int t = 0; t < 1024; ++t) {
        const int par = t & 1;
        u64* mb_self = mbox + (size_t)(((b << 1) | par) * 4 + p)    * 128;
        const u64* mb_peer = mbox + (size_t)(((b << 1) | par) * 4 + peer) * 128;

        // prefetch xp (lives in out until we overwrite it with h)
        const float xA = stA[(size_t)t * 512];
        const float xB = stA[(size_t)t * 512 + 16];

        // --- A: y = h_read . W_slice^T, 4 accumulator chains (halved dep chain)
        f32x4 a0a = (f32x4){0,0,0,0}, a0b = (f32x4){0,0,0,0};
        f32x4 a1a = (f32x4){0,0,0,0}, a1b = (f32x4){0,0,0,0};
#pragma unroll
        for (int kt = 0; kt < 8; ++kt) {
            bf16x8 a = *(const bf16x8*)&hread[kt * 32 + kq * 8];
            a0a = __builtin_amdgcn_mfma_f32_16x16x32_bf16(a, wf0[kt], a0a, 0, 0, 0);
            a1a = __builtin_amdgcn_mfma_f32_16x16x32_bf16(a, wf1[kt], a1a, 0, 0, 0);
        }
#pragma unroll
        for (int kt = 8; kt < 16; ++kt) {
            bf16x8 a = *(const bf16x8*)&hread[kt * 32 + kq * 8];
            a0b = __builtin_amdgcn_mfma_f32_16x16x32_bf16(a, wf0[kt], a0b, 0, 0, 0);
            a1b = __builtin_amdgcn_mfma_f32_16x16x32_bf16(a, wf1[kt], a1b, 0, 0, 0);
        }

        const int rm1 = (t + 3) & 3, rm2 = (t + 2) & 3, rm3 = (t + 1) & 3, rt = t & 3;

        // --- B: tanh, ship to mailbox IMMEDIATELY, then states + own hist
        if (lane < 16) {
            const float hAv = tanhf(xA + a0a[0] + a0b[0] + bA);
            const float hBv = tanhf(xB + a1a[0] + a1b[0] + bB);
            const u64 tag = (u64)(unsigned)(t + 1) << 32;
            union { float f; unsigned u; } cA, cB;
            cA.f = hAv; cB.f = hBv;
            __hip_atomic_store(&mb_self[wave * 32 + col],      tag | cA.u, __ATOMIC_RELAXED, AGENT);
            __hip_atomic_store(&mb_self[wave * 32 + col + 16], tag | cB.u, __ATOMIC_RELAXED, AGENT);
            stA[(size_t)t * 512]      = hAv;
            stA[(size_t)t * 512 + 16] = hBv;
            hist[rt][hA] = hAv;
            hist[rt][hB] = hBv;
        }

        // --- E1: partial Lagrange combine from h(t-1..t-3) (old rows, stable)
        const float pp0 = k1 * hist[rm1][i0]     + k2 * hist[rm2][i0]     + k3 * hist[rm3][i0];
        const float pp1 = k1 * hist[rm1][i0 + 1] + k2 * hist[rm2][i0 + 1] + k3 * hist[rm3][i0 + 1];

        // --- C: waves 1..3 poll one peer each (2 tagged u64 per lane)
        if (wave != 0) {
            const unsigned want = (unsigned)(t + 1);
            u64 v0, v1;
            do { v0 = __hip_atomic_load(&mb_peer[lane * 2],     __ATOMIC_RELAXED, AGENT); }
            while ((unsigned)(v0 >> 32) != want);
            do { v1 = __hip_atomic_load(&mb_peer[lane * 2 + 1], __ATOMIC_RELAXED, AGENT); }
            while ((unsigned)(v1 >> 32) != want);
            union { unsigned u; float f; } d0, d1;
            d0.u = (unsigned)v0; d1.u = (unsigned)v1;
            hist[rt][peer * 128 + lane * 2]     = d0.f;
            hist[rt][peer * 128 + lane * 2 + 1] = d1.f;
        }
        __syncthreads();

        // --- E2: finish h_read(t+1) = pp + k0*h(t), round to bf16 for MFMA
        hread[i0]     = (__bf16)(pp0 + k0 * hist[rt][i0]);
        hread[i0 + 1] = (__bf16)(pp1 + k0 * hist[rt][i0 + 1]);
        __syncthreads();
    }

    // final state output: h(1023) sits in hist[1023 & 3 == 3]
    float* out2 = out + (size_t)32 * 1024 * 512 + (size_t)b * 512;
    out2[i0]     = hist[3][i0];
    out2[i0 + 1] = hist[3][i0 + 1];
}

// ---------------------------------------------------------------------------
extern "C" void kernel_launch(void* const* d_in, const int* in_sizes, int n_in,
                              void* d_out, int out_size, void* d_ws, size_t ws_size,
                              hipStream_t stream) {
    const float* x    = (const float*)d_in[0];   // [32,1024,512]
    const float* Wih  = (const float*)d_in[1];   // [512,512]
    const float* Whh  = (const float*)d_in[2];   // [512,512]
    const float* bih  = (const float*)d_in[3];   // [512]
    const float* bhh  = (const float*)d_in[4];   // [512]
    const float* kern = (const float*)d_in[5];   // [4]
    float* out = (float*)d_out;

    // mailboxes: 32 batches x 2 parity x 4 slices x 128 tagged u64 = 256 KB.
    // No init needed: polls exact-match tag (t+1), 0xAAAAAAAA poison can't match.
    u64* mbox = (u64*)d_ws;

    dim3 g1(512, 8, 1);   // (BT/64, H/64)
    xproj_gemm_kernel<<<g1, 256, 0, stream>>>(x, Wih, bih, out);
    lagrange_rnn_kernel<<<128, 256, 0, stream>>>(Whh, bhh, kern, out, mbox);
}

// Round 4
// 1804.279 us; speedup vs baseline: 2.3077x; 1.1403x over previous
//
#include <hip/hip_runtime.h>

typedef __bf16 bf16x8 __attribute__((ext_vector_type(8)));
typedef float  f32x4  __attribute__((ext_vector_type(4)));
typedef unsigned long long u64;

#define AGENT __HIP_MEMORY_SCOPE_AGENT

__device__ __forceinline__ float fast_tanh(float x) {
    // tanh(x) = 1 - 2/(exp(2x)+1); exp via v_exp_f32, rcp via v_rcp_f32.
    // Large |x| degrades gracefully (inf -> 1, 0 -> -1). ~1e-6 abs error.
    float e = __expf(2.0f * x);
    return 1.0f - 2.0f * __builtin_amdgcn_rcpf(e + 1.0f);
}

// ---------------------------------------------------------------------------
// Kernel 1: xproj = x @ Wih^T + bih, written fp32 directly into d_out's
// states region (kernel 2 reads it there and overwrites in place with h).
// ---------------------------------------------------------------------------
__global__ __launch_bounds__(256) void xproj_gemm_kernel(
    const float* __restrict__ x, const float* __restrict__ Wih,
    const float* __restrict__ bih, float* __restrict__ out)
{
    __shared__ __bf16 Ash[64][72];
    __shared__ __bf16 Bsh[64][72];

    const int tid  = threadIdx.x;
    const int wave = tid >> 6, lane = tid & 63;
    const int col  = lane & 15, kq = lane >> 4;
    const int bt0  = blockIdx.x * 64;
    const int h0   = blockIdx.y * 64;

    f32x4 acc[4];
#pragma unroll
    for (int nt = 0; nt < 4; ++nt) acc[nt] = (f32x4){0.f, 0.f, 0.f, 0.f};

    const int r  = tid >> 2;
    const int cb = (tid & 3) * 16;

    for (int k0 = 0; k0 < 512; k0 += 64) {
        const float* ax = x   + (size_t)(bt0 + r) * 512 + k0 + cb;
        const float* bx = Wih + (size_t)(h0  + r) * 512 + k0 + cb;
#pragma unroll
        for (int j = 0; j < 4; ++j) {
            const float4 av = ((const float4*)ax)[j];
            const float4 bv = ((const float4*)bx)[j];
            const int c = cb + 4 * j;
            Ash[r][c+0]=(__bf16)av.x; Ash[r][c+1]=(__bf16)av.y;
            Ash[r][c+2]=(__bf16)av.z; Ash[r][c+3]=(__bf16)av.w;
            Bsh[r][c+0]=(__bf16)bv.x; Bsh[r][c+1]=(__bf16)bv.y;
            Bsh[r][c+2]=(__bf16)bv.z; Bsh[r][c+3]=(__bf16)bv.w;
        }
        __syncthreads();
#pragma unroll
        for (int kt = 0; kt < 2; ++kt) {
            bf16x8 a = *(const bf16x8*)&Ash[wave * 16 + col][kt * 32 + kq * 8];
#pragma unroll
            for (int nt = 0; nt < 4; ++nt) {
                bf16x8 bb = *(const bf16x8*)&Bsh[nt * 16 + col][kt * 32 + kq * 8];
                acc[nt] = __builtin_amdgcn_mfma_f32_16x16x32_bf16(a, bb, acc[nt], 0, 0, 0);
            }
        }
        __syncthreads();
    }
#pragma unroll
    for (int nt = 0; nt < 4; ++nt) {
        const float bv = bih[h0 + nt * 16 + col];
#pragma unroll
        for (int reg = 0; reg < 4; ++reg) {
            const int m = bt0 + wave * 16 + kq * 4 + reg;
            out[(size_t)m * 512 + h0 + nt * 16 + col] = acc[nt][reg] + bv;
        }
    }
}

// ---------------------------------------------------------------------------
// Kernel 2: recurrence. 128 blocks = 32 batches x 4 weight-stationary slices.
// Single barrier per step: hread(t+1) is double-buffered by parity and built
// directly by the value producers/receivers (Lagrange partial pp precomputed
// from old hist rows before the MFMA). Exchange = fence-free tagged-u64
// mailboxes; stA stores + xp prefetch deferred past the poll so vmcnt drain
// in the tag-check never waits on HBM stores.
// ---------------------------------------------------------------------------
__global__ __launch_bounds__(256) void lagrange_rnn_kernel(
    const float* __restrict__ Whh, const float* __restrict__ bhh,
    const float* __restrict__ kern, float* __restrict__ out,
    u64* __restrict__ mbox)
{
    const int id   = blockIdx.x;                 // 0..127
    const int b    = (id & 7) + ((id >> 5) << 3);// batch 0..31 (group on one XCD)
    const int p    = (id >> 3) & 3;              // slice member 0..3
    const int tid  = threadIdx.x;
    const int wave = tid >> 6, lane = tid & 63;
    const int col  = lane & 15, kq = lane >> 4;

    __shared__ float  hist[4][512];    // circular h history, fp32
    __shared__ __bf16 hread[2][512];   // parity double-buffered MFMA A operand

    for (int i = tid; i < 2048; i += 256) ((float*)hist)[i] = 0.f;
    for (int i = tid; i < 1024; i += 256) { hread[0][i & 511] = (__bf16)0.f; hread[1][i & 511] = (__bf16)0.f; }

    // --- weight fragments (once): wave w owns houts [p*128+w*32, +32)
    const int hA = p * 128 + wave * 32 + col;
    const int hB = hA + 16;
    bf16x8 wf0[16], wf1[16];
#pragma unroll
    for (int kt = 0; kt < 16; ++kt) {
        const float* s0 = Whh + (size_t)hA * 512 + kt * 32 + kq * 8;
        const float* s1 = Whh + (size_t)hB * 512 + kt * 32 + kq * 8;
        const float4 a0 = *(const float4*)s0, a1 = *(const float4*)(s0 + 4);
        const float4 b0 = *(const float4*)s1, b1 = *(const float4*)(s1 + 4);
        bf16x8 w;
        w[0]=(__bf16)a0.x; w[1]=(__bf16)a0.y; w[2]=(__bf16)a0.z; w[3]=(__bf16)a0.w;
        w[4]=(__bf16)a1.x; w[5]=(__bf16)a1.y; w[6]=(__bf16)a1.z; w[7]=(__bf16)a1.w;
        wf0[kt] = w;
        w[0]=(__bf16)b0.x; w[1]=(__bf16)b0.y; w[2]=(__bf16)b0.z; w[3]=(__bf16)b0.w;
        w[4]=(__bf16)b1.x; w[5]=(__bf16)b1.y; w[6]=(__bf16)b1.z; w[7]=(__bf16)b1.w;
        wf1[kt] = w;
    }
    const float k0 = kern[0], k1 = kern[1], k2 = kern[2], k3 = kern[3];
    const float bA = bhh[hA], bB = bhh[hB];
    float* stA = out + (size_t)b * 1024 * 512 + hA;
    const int i0 = tid * 2;
    const int peer = (p + wave) & 3;              // waves 1..3 poll this peer
    const int j0 = peer * 128 + lane * 2;         // poll-deposit indices
    const bool comp = (lane < 16);
    __syncthreads();

    float xA = stA[0], xB = stA[16];              // xp(0) prefetch

    for (int t = 0; t < 1024; ++t) {
        const int rm1 = (t + 3) & 3, rm2 = (t + 2) & 3, rm3 = (t + 1) & 3, rt = t & 3;
        const int rb = t & 1, wb = rb ^ 1;        // hread read/write buffers
        u64* mb_self = mbox + (size_t)(((b << 1) | rb) * 4 + p)    * 128;
        const u64* mb_peer = mbox + (size_t)(((b << 1) | rb) * 4 + peer) * 128;

        // --- Lagrange partials from finalized hist rows (off the critical tail)
        float ppA = 0.f, ppB = 0.f, ppP0 = 0.f, ppP1 = 0.f;
        if (comp) {
            ppA = k1 * hist[rm1][hA] + k2 * hist[rm2][hA] + k3 * hist[rm3][hA];
            ppB = k1 * hist[rm1][hB] + k2 * hist[rm2][hB] + k3 * hist[rm3][hB];
        }
        if (wave != 0) {
            ppP0 = k1 * hist[rm1][j0]     + k2 * hist[rm2][j0]     + k3 * hist[rm3][j0];
            ppP1 = k1 * hist[rm1][j0 + 1] + k2 * hist[rm2][j0 + 1] + k3 * hist[rm3][j0 + 1];
        }

        // --- MFMA: y = h_read . W_slice^T (4 acc chains)
        f32x4 a0a = (f32x4){0,0,0,0}, a0b = (f32x4){0,0,0,0};
        f32x4 a1a = (f32x4){0,0,0,0}, a1b = (f32x4){0,0,0,0};
#pragma unroll
        for (int kt = 0; kt < 8; ++kt) {
            bf16x8 a = *(const bf16x8*)&hread[rb][kt * 32 + kq * 8];
            a0a = __builtin_amdgcn_mfma_f32_16x16x32_bf16(a, wf0[kt], a0a, 0, 0, 0);
            a1a = __builtin_amdgcn_mfma_f32_16x16x32_bf16(a, wf1[kt], a1a, 0, 0, 0);
        }
#pragma unroll
        for (int kt = 8; kt < 16; ++kt) {
            bf16x8 a = *(const bf16x8*)&hread[rb][kt * 32 + kq * 8];
            a0b = __builtin_amdgcn_mfma_f32_16x16x32_bf16(a, wf0[kt], a0b, 0, 0, 0);
            a1b = __builtin_amdgcn_mfma_f32_16x16x32_bf16(a, wf1[kt], a1b, 0, 0, 0);
        }

        float hAv = 0.f, hBv = 0.f;
        if (comp) {
            hAv = fast_tanh(xA + a0a[0] + a0b[0] + bA);
            hBv = fast_tanh(xB + a1a[0] + a1b[0] + bB);
            const u64 tag = (u64)(unsigned)(t + 1) << 32;
            union { float f; unsigned u; } cA, cB;
            cA.f = hAv; cB.f = hBv;
            __hip_atomic_store(&mb_self[wave * 32 + col],      tag | cA.u, __ATOMIC_RELAXED, AGENT);
            __hip_atomic_store(&mb_self[wave * 32 + col + 16], tag | cB.u, __ATOMIC_RELAXED, AGENT);
            hist[rt][hA] = hAv;  hread[wb][hA] = (__bf16)(ppA + k0 * hAv);
            hist[rt][hB] = hBv;  hread[wb][hB] = (__bf16)(ppB + k0 * hBv);
        }

        // --- poll one peer (both u64 issued per iteration -> 1 RTT)
        if (wave != 0) {
            const unsigned want = (unsigned)(t + 1);
            u64 v0, v1;
            do {
                v0 = __hip_atomic_load(&mb_peer[lane * 2],     __ATOMIC_RELAXED, AGENT);
                v1 = __hip_atomic_load(&mb_peer[lane * 2 + 1], __ATOMIC_RELAXED, AGENT);
            } while ((unsigned)(v0 >> 32) != want || (unsigned)(v1 >> 32) != want);
            union { unsigned u; float f; } d0, d1;
            d0.u = (unsigned)v0; d1.u = (unsigned)v1;
            hist[rt][j0]     = d0.f;  hread[wb][j0]     = (__bf16)(ppP0 + k0 * d0.f);
            hist[rt][j0 + 1] = d1.f;  hread[wb][j0 + 1] = (__bf16)(ppP1 + k0 * d1.f);
        }

        // --- deferred HBM traffic (never gates the tag check)
        if (comp) {
            stA[(size_t)t * 512]      = hAv;
            stA[(size_t)t * 512 + 16] = hBv;
            xA = stA[(size_t)(t + 1) * 512];        // xp(t+1) prefetch
            xB = stA[(size_t)(t + 1) * 512 + 16];   // (t=1023: in-bounds, unused)
        }
        __syncthreads();
    }

    // final state output: h(1023) sits in hist[3]
    float* out2 = out + (size_t)32 * 1024 * 512 + (size_t)b * 512;
    out2[i0]     = hist[3][i0];
    out2[i0 + 1] = hist[3][i0 + 1];
}

// ---------------------------------------------------------------------------
extern "C" void kernel_launch(void* const* d_in, const int* in_sizes, int n_in,
                              void* d_out, int out_size, void* d_ws, size_t ws_size,
                              hipStream_t stream) {
    const float* x    = (const float*)d_in[0];   // [32,1024,512]
    const float* Wih  = (const float*)d_in[1];   // [512,512]
    const float* Whh  = (const float*)d_in[2];   // [512,512]
    const float* bih  = (const float*)d_in[3];   // [512]
    const float* bhh  = (const float*)d_in[4];   // [512]
    const float* kern = (const float*)d_in[5];   // [4]
    float* out = (float*)d_out;

    // mailboxes: 32 batches x 2 parity x 4 slices x 128 tagged u64 = 256 KB.
    // No init needed: exact tag match (t+1); 0xAAAAAAAA poison can't match.
    u64* mbox = (u64*)d_ws;

    dim3 g1(512, 8, 1);
    xproj_gemm_kernel<<<g1, 256, 0, stream>>>(x, Wih, bih, out);
    lagrange_rnn_kernel<<<128, 256, 0, stream>>>(Whh, bhh, kern, out, mbox);
}

// Round 5
// 1672.088 us; speedup vs baseline: 2.4902x; 1.0791x over previous
//
#include <hip/hip_runtime.h>

typedef __bf16 bf16x8 __attribute__((ext_vector_type(8)));
typedef float  f32x4  __attribute__((ext_vector_type(4)));
typedef unsigned long long u64;

#define AGENT __HIP_MEMORY_SCOPE_AGENT

__device__ __forceinline__ float fast_tanh(float x) {
    float e = __expf(2.0f * x);
    return 1.0f - 2.0f * __builtin_amdgcn_rcpf(e + 1.0f);
}

// ---------------------------------------------------------------------------
// Kernel 1: xproj = x @ Wih^T + bih -> fp32 into d_out's states region.
// ---------------------------------------------------------------------------
__global__ __launch_bounds__(256) void xproj_gemm_kernel(
    const float* __restrict__ x, const float* __restrict__ Wih,
    const float* __restrict__ bih, float* __restrict__ out)
{
    __shared__ __bf16 Ash[64][72];
    __shared__ __bf16 Bsh[64][72];

    const int tid  = threadIdx.x;
    const int wave = tid >> 6, lane = tid & 63;
    const int col  = lane & 15, kq = lane >> 4;
    const int bt0  = blockIdx.x * 64;
    const int h0   = blockIdx.y * 64;

    f32x4 acc[4];
#pragma unroll
    for (int nt = 0; nt < 4; ++nt) acc[nt] = (f32x4){0.f, 0.f, 0.f, 0.f};

    const int r  = tid >> 2;
    const int cb = (tid & 3) * 16;

    for (int k0 = 0; k0 < 512; k0 += 64) {
        const float* ax = x   + (size_t)(bt0 + r) * 512 + k0 + cb;
        const float* bx = Wih + (size_t)(h0  + r) * 512 + k0 + cb;
#pragma unroll
        for (int j = 0; j < 4; ++j) {
            const float4 av = ((const float4*)ax)[j];
            const float4 bv = ((const float4*)bx)[j];
            const int c = cb + 4 * j;
            Ash[r][c+0]=(__bf16)av.x; Ash[r][c+1]=(__bf16)av.y;
            Ash[r][c+2]=(__bf16)av.z; Ash[r][c+3]=(__bf16)av.w;
            Bsh[r][c+0]=(__bf16)bv.x; Bsh[r][c+1]=(__bf16)bv.y;
            Bsh[r][c+2]=(__bf16)bv.z; Bsh[r][c+3]=(__bf16)bv.w;
        }
        __syncthreads();
#pragma unroll
        for (int kt = 0; kt < 2; ++kt) {
            bf16x8 a = *(const bf16x8*)&Ash[wave * 16 + col][kt * 32 + kq * 8];
#pragma unroll
            for (int nt = 0; nt < 4; ++nt) {
                bf16x8 bb = *(const bf16x8*)&Bsh[nt * 16 + col][kt * 32 + kq * 8];
                acc[nt] = __builtin_amdgcn_mfma_f32_16x16x32_bf16(a, bb, acc[nt], 0, 0, 0);
            }
        }
        __syncthreads();
    }
#pragma unroll
    for (int nt = 0; nt < 4; ++nt) {
        const float bv = bih[h0 + nt * 16 + col];
#pragma unroll
        for (int reg = 0; reg < 4; ++reg) {
            const int m = bt0 + wave * 16 + kq * 4 + reg;
            out[(size_t)m * 512 + h0 + nt * 16 + col] = acc[nt][reg] + bv;
        }
    }
}

// ---------------------------------------------------------------------------
// Kernel 2: recurrence. 128 blocks = 32 batches x 4 weight-stationary slices.
// Step schedule (all HBM traffic overlapped with the exchange wait):
//   top:   issue xp(t+1) prefetch; Lagrange partials from old hist rows
//   MFMA:  y = hread(t) . W_slice^T
//   tanh -> mailbox store (LLC) -> stA store (L2) -> LDS hist/hread deposit
//   poll peer mailbox (tagged u64, fence-free)
//   LDS deposit of peer values -> single barrier (nothing left to drain)
// ---------------------------------------------------------------------------
__global__ __launch_bounds__(256) void lagrange_rnn_kernel(
    const float* __restrict__ Whh, const float* __restrict__ bhh,
    const float* __restrict__ kern, float* __restrict__ out,
    u64* __restrict__ mbox)
{
    const int id   = blockIdx.x;                 // 0..127
    const int b    = (id & 7) + ((id >> 5) << 3);// batch 0..31 (group on one XCD)
    const int p    = (id >> 3) & 3;              // slice member 0..3
    const int tid  = threadIdx.x;
    const int wave = tid >> 6, lane = tid & 63;
    const int col  = lane & 15, kq = lane >> 4;

    __shared__ float  hist[4][512];    // circular h history, fp32
    __shared__ __bf16 hread[2][512];   // parity double-buffered MFMA A operand

    for (int i = tid; i < 2048; i += 256) ((float*)hist)[i] = 0.f;
    for (int i = tid; i < 512;  i += 256) { hread[0][i] = (__bf16)0.f; hread[1][i] = (__bf16)0.f; }

    // --- weight fragments (once): wave w owns houts [p*128+w*32, +32)
    const int hA = p * 128 + wave * 32 + col;
    const int hB = hA + 16;
    bf16x8 wf0[16], wf1[16];
#pragma unroll
    for (int kt = 0; kt < 16; ++kt) {
        const float* s0 = Whh + (size_t)hA * 512 + kt * 32 + kq * 8;
        const float* s1 = Whh + (size_t)hB * 512 + kt * 32 + kq * 8;
        const float4 a0 = *(const float4*)s0, a1 = *(const float4*)(s0 + 4);
        const float4 b0 = *(const float4*)s1, b1 = *(const float4*)(s1 + 4);
        bf16x8 w;
        w[0]=(__bf16)a0.x; w[1]=(__bf16)a0.y; w[2]=(__bf16)a0.z; w[3]=(__bf16)a0.w;
        w[4]=(__bf16)a1.x; w[5]=(__bf16)a1.y; w[6]=(__bf16)a1.z; w[7]=(__bf16)a1.w;
        wf0[kt] = w;
        w[0]=(__bf16)b0.x; w[1]=(__bf16)b0.y; w[2]=(__bf16)b0.z; w[3]=(__bf16)b0.w;
        w[4]=(__bf16)b1.x; w[5]=(__bf16)b1.y; w[6]=(__bf16)b1.z; w[7]=(__bf16)b1.w;
        wf1[kt] = w;
    }
    const float k0 = kern[0], k1 = kern[1], k2 = kern[2], k3 = kern[3];
    const float bA = bhh[hA], bB = bhh[hB];
    float* stA = out + (size_t)b * 1024 * 512 + hA;
    const int i0 = tid * 2;
    const int peer = (p + wave) & 3;              // waves 1..3 poll this peer
    const int j0 = peer * 128 + lane * 2;
    const bool comp = (lane < 16);
    __syncthreads();

    float xA = 0.f, xB = 0.f;
    if (comp) { xA = stA[0]; xB = stA[16]; }      // xp(0)

    for (int t = 0; t < 1024; ++t) {
        const int rm1 = (t + 3) & 3, rm2 = (t + 2) & 3, rm3 = (t + 1) & 3, rt = t & 3;
        const int rb = t & 1, wb = rb ^ 1;
        u64* mb_self = mbox + (size_t)(((b << 1) | rb) * 4 + p)    * 128;
        const u64* mb_peer = mbox + (size_t)(((b << 1) | rb) * 4 + peer) * 128;

        // --- issue xp(t+1) prefetch FIRST: ~900cyc HBM latency overlaps
        //     MFMA + tanh + poll; nothing left to drain at the barrier.
        float nxA = 0.f, nxB = 0.f;
        if (comp) {
            nxA = stA[(size_t)(t + 1) * 512];
            nxB = stA[(size_t)(t + 1) * 512 + 16];
        }

        // --- Lagrange partials from finalized hist rows
        float ppA = 0.f, ppB = 0.f, ppP0 = 0.f, ppP1 = 0.f;
        if (comp) {
            ppA = k1 * hist[rm1][hA] + k2 * hist[rm2][hA] + k3 * hist[rm3][hA];
            ppB = k1 * hist[rm1][hB] + k2 * hist[rm2][hB] + k3 * hist[rm3][hB];
        }
        if (wave != 0) {
            ppP0 = k1 * hist[rm1][j0]     + k2 * hist[rm2][j0]     + k3 * hist[rm3][j0];
            ppP1 = k1 * hist[rm1][j0 + 1] + k2 * hist[rm2][j0 + 1] + k3 * hist[rm3][j0 + 1];
        }

        // --- MFMA: y = h_read . W_slice^T (4 acc chains)
        f32x4 a0a = (f32x4){0,0,0,0}, a0b = (f32x4){0,0,0,0};
        f32x4 a1a = (f32x4){0,0,0,0}, a1b = (f32x4){0,0,0,0};
#pragma unroll
        for (int kt = 0; kt < 8; ++kt) {
            bf16x8 a = *(const bf16x8*)&hread[rb][kt * 32 + kq * 8];
            a0a = __builtin_amdgcn_mfma_f32_16x16x32_bf16(a, wf0[kt], a0a, 0, 0, 0);
            a1a = __builtin_amdgcn_mfma_f32_16x16x32_bf16(a, wf1[kt], a1a, 0, 0, 0);
        }
#pragma unroll
        for (int kt = 8; kt < 16; ++kt) {
            bf16x8 a = *(const bf16x8*)&hread[rb][kt * 32 + kq * 8];
            a0b = __builtin_amdgcn_mfma_f32_16x16x32_bf16(a, wf0[kt], a0b, 0, 0, 0);
            a1b = __builtin_amdgcn_mfma_f32_16x16x32_bf16(a, wf1[kt], a1b, 0, 0, 0);
        }

        // --- tanh -> ship to LLC mailbox, HBM states, LDS (all pre-poll)
        if (comp) {
            const float hAv = fast_tanh(xA + a0a[0] + a0b[0] + bA);
            const float hBv = fast_tanh(xB + a1a[0] + a1b[0] + bB);
            const u64 tag = (u64)(unsigned)(t + 1) << 32;
            union { float f; unsigned u; } cA, cB;
            cA.f = hAv; cB.f = hBv;
            __hip_atomic_store(&mb_self[wave * 32 + col],      tag | cA.u, __ATOMIC_RELAXED, AGENT);
            __hip_atomic_store(&mb_self[wave * 32 + col + 16], tag | cB.u, __ATOMIC_RELAXED, AGENT);
            stA[(size_t)t * 512]      = hAv;
            stA[(size_t)t * 512 + 16] = hBv;
            hist[rt][hA] = hAv;  hread[wb][hA] = (__bf16)(ppA + k0 * hAv);
            hist[rt][hB] = hBv;  hread[wb][hB] = (__bf16)(ppB + k0 * hBv);
        }

        // --- poll one peer (both u64 per iteration -> 1 RTT)
        if (wave != 0) {
            const unsigned want = (unsigned)(t + 1);
            u64 v0, v1;
            do {
                v0 = __hip_atomic_load(&mb_peer[lane * 2],     __ATOMIC_RELAXED, AGENT);
                v1 = __hip_atomic_load(&mb_peer[lane * 2 + 1], __ATOMIC_RELAXED, AGENT);
            } while ((unsigned)(v0 >> 32) != want || (unsigned)(v1 >> 32) != want);
            union { unsigned u; float f; } d0, d1;
            d0.u = (unsigned)v0; d1.u = (unsigned)v1;
            hist[rt][j0]     = d0.f;  hread[wb][j0]     = (__bf16)(ppP0 + k0 * d0.f);
            hist[rt][j0 + 1] = d1.f;  hread[wb][j0 + 1] = (__bf16)(ppP1 + k0 * d1.f);
        }

        xA = nxA; xB = nxB;
        __syncthreads();
    }

    // final state output: h(1023) sits in hist[3]
    float* out2 = out + (size_t)32 * 1024 * 512 + (size_t)b * 512;
    out2[i0]     = hist[3][i0];
    out2[i0 + 1] = hist[3][i0 + 1];
}

// ---------------------------------------------------------------------------
extern "C" void kernel_launch(void* const* d_in, const int* in_sizes, int n_in,
                              void* d_out, int out_size, void* d_ws, size_t ws_size,
                              hipStream_t stream) {
    const float* x    = (const float*)d_in[0];   // [32,1024,512]
    const float* Wih  = (const float*)d_in[1];   // [512,512]
    const float* Whh  = (const float*)d_in[2];   // [512,512]
    const float* bih  = (const float*)d_in[3];   // [512]
    const float* bhh  = (const float*)d_in[4];   // [512]
    const float* kern = (const float*)d_in[5];   // [4]
    float* out = (float*)d_out;

    // mailboxes: 32 batches x 2 parity x 4 slices x 128 tagged u64 = 256 KB.
    // No init needed: exact tag match (t+1); 0xAAAAAAAA poison can't match.
    u64* mbox = (u64*)d_ws;

    dim3 g1(512, 8, 1);
    xproj_gemm_kernel<<<g1, 256, 0, stream>>>(x, Wih, bih, out);
    lagrange_rnn_kernel<<<128, 256, 0, stream>>>(Whh, bhh, kern, out, mbox);
}

// Round 6
// 1579.938 us; speedup vs baseline: 2.6354x; 1.0583x over previous
//
#include <hip/hip_runtime.h>

typedef __bf16 bf16x8 __attribute__((ext_vector_type(8)));
typedef float  f32x4  __attribute__((ext_vector_type(4)));
typedef unsigned long long u64;

#define AGENT __HIP_MEMORY_SCOPE_AGENT

__device__ __forceinline__ float fast_tanh(float x) {
    float e = __expf(2.0f * x);
    return 1.0f - 2.0f * __builtin_amdgcn_rcpf(e + 1.0f);
}

// ---------------------------------------------------------------------------
// Kernel 1: xproj = x @ Wih^T + bih -> fp32 into d_out's states region.
// ---------------------------------------------------------------------------
__global__ __launch_bounds__(256) void xproj_gemm_kernel(
    const float* __restrict__ x, const float* __restrict__ Wih,
    const float* __restrict__ bih, float* __restrict__ out)
{
    __shared__ __bf16 Ash[64][72];
    __shared__ __bf16 Bsh[64][72];

    const int tid  = threadIdx.x;
    const int wave = tid >> 6, lane = tid & 63;
    const int col  = lane & 15, kq = lane >> 4;
    const int bt0  = blockIdx.x * 64;
    const int h0   = blockIdx.y * 64;

    f32x4 acc[4];
#pragma unroll
    for (int nt = 0; nt < 4; ++nt) acc[nt] = (f32x4){0.f, 0.f, 0.f, 0.f};

    const int r  = tid >> 2;
    const int cb = (tid & 3) * 16;

    for (int k0 = 0; k0 < 512; k0 += 64) {
        const float* ax = x   + (size_t)(bt0 + r) * 512 + k0 + cb;
        const float* bx = Wih + (size_t)(h0  + r) * 512 + k0 + cb;
#pragma unroll
        for (int j = 0; j < 4; ++j) {
            const float4 av = ((const float4*)ax)[j];
            const float4 bv = ((const float4*)bx)[j];
            const int c = cb + 4 * j;
            Ash[r][c+0]=(__bf16)av.x; Ash[r][c+1]=(__bf16)av.y;
            Ash[r][c+2]=(__bf16)av.z; Ash[r][c+3]=(__bf16)av.w;
            Bsh[r][c+0]=(__bf16)bv.x; Bsh[r][c+1]=(__bf16)bv.y;
            Bsh[r][c+2]=(__bf16)bv.z; Bsh[r][c+3]=(__bf16)bv.w;
        }
        __syncthreads();
#pragma unroll
        for (int kt = 0; kt < 2; ++kt) {
            bf16x8 a = *(const bf16x8*)&Ash[wave * 16 + col][kt * 32 + kq * 8];
#pragma unroll
            for (int nt = 0; nt < 4; ++nt) {
                bf16x8 bb = *(const bf16x8*)&Bsh[nt * 16 + col][kt * 32 + kq * 8];
                acc[nt] = __builtin_amdgcn_mfma_f32_16x16x32_bf16(a, bb, acc[nt], 0, 0, 0);
            }
        }
        __syncthreads();
    }
#pragma unroll
    for (int nt = 0; nt < 4; ++nt) {
        const float bv = bih[h0 + nt * 16 + col];
#pragma unroll
        for (int reg = 0; reg < 4; ++reg) {
            const int m = bt0 + wave * 16 + kq * 4 + reg;
            out[(size_t)m * 512 + h0 + nt * 16 + col] = acc[nt][reg] + bv;
        }
    }
}

// ---------------------------------------------------------------------------
// Kernel 2: recurrence. 128 blocks = 32 batches x 4 weight-stationary slices.
// Two-phase K-ordered step: weight fragment j holds global K-tile (4p+j)&15,
// so j=0..3 is the block's OWN slice (operands local) and j=4..15 are peers.
// Per step:
//   barA -> phase-1 MFMA own-K  (overlaps peer data flight)
//        -> poll peers' h(t-1) (tagged u64, fence-free) -> deposit hread/hist
//   barB -> xp(t+1) prefetch -> phase-2 MFMA peer-K -> tanh
//        -> mailbox ship h(t) -> states store -> own hread(t+1)/hist deposit
// ---------------------------------------------------------------------------
__global__ __launch_bounds__(256) void lagrange_rnn_kernel(
    const float* __restrict__ Whh, const float* __restrict__ bhh,
    const float* __restrict__ kern, float* __restrict__ out,
    u64* __restrict__ mbox)
{
    const int id   = blockIdx.x;                 // 0..127
    const int b    = (id & 7) + ((id >> 5) << 3);// batch 0..31 (group on one XCD)
    const int p    = (id >> 3) & 3;              // slice member 0..3
    const int tid  = threadIdx.x;
    const int wave = tid >> 6, lane = tid & 63;
    const int col  = lane & 15, kq = lane >> 4;

    __shared__ float  hist[4][512];    // circular h history, fp32
    __shared__ __bf16 hread[2][512];   // parity double-buffered MFMA A operand

    for (int i = tid; i < 2048; i += 256) ((float*)hist)[i] = 0.f;
    for (int i = tid; i < 512;  i += 256) { hread[0][i] = (__bf16)0.f; hread[1][i] = (__bf16)0.f; }

    // --- weight fragments, K-reordered: wf[j] <-> global K-tile (4p+j)&15
    const int hA = p * 128 + wave * 32 + col;
    const int hB = hA + 16;
    bf16x8 wf0[16], wf1[16];
#pragma unroll
    for (int j = 0; j < 16; ++j) {
        const int ktg = ((j + 4 * p) & 15) * 32 + kq * 8;
        const float* s0 = Whh + (size_t)hA * 512 + ktg;
        const float* s1 = Whh + (size_t)hB * 512 + ktg;
        const float4 a0 = *(const float4*)s0, a1 = *(const float4*)(s0 + 4);
        const float4 b0 = *(const float4*)s1, b1 = *(const float4*)(s1 + 4);
        bf16x8 w;
        w[0]=(__bf16)a0.x; w[1]=(__bf16)a0.y; w[2]=(__bf16)a0.z; w[3]=(__bf16)a0.w;
        w[4]=(__bf16)a1.x; w[5]=(__bf16)a1.y; w[6]=(__bf16)a1.z; w[7]=(__bf16)a1.w;
        wf0[j] = w;
        w[0]=(__bf16)b0.x; w[1]=(__bf16)b0.y; w[2]=(__bf16)b0.z; w[3]=(__bf16)b0.w;
        w[4]=(__bf16)b1.x; w[5]=(__bf16)b1.y; w[6]=(__bf16)b1.z; w[7]=(__bf16)b1.w;
        wf1[j] = w;
    }
    const float k0 = kern[0], k1 = kern[1], k2 = kern[2], k3 = kern[3];
    const float bA = bhh[hA], bB = bhh[hB];
    float* stA = out + (size_t)b * 1024 * 512 + hA;
    const int peer = (p + wave) & 3;              // waves 1..3 poll this peer
    const int j0 = peer * 128 + lane * 2;
    const bool comp = (lane < 16);
    // hread element index base for A operand of wf[j]: ((4p+j)&15)*32 + kq*8
    const int abase = p * 128 + kq * 8;           // j-th A addr = (abase + 32j) & 511

    float xA = 0.f, xB = 0.f;
    __syncthreads();
    if (comp) { xA = stA[0]; xB = stA[16]; }      // xp(0)

    for (int t = 0; t < 1024; ++t) {
        const int rb = t & 1, wb = rb ^ 1;
        const int rt = t & 3;
        const int rm1 = (t + 3) & 3, rm2 = (t + 2) & 3, rm3 = (t + 1) & 3;
        const u64* mb_peer = mbox + (size_t)(((b << 1) | rb) * 4 + peer) * 128;

        __syncthreads();   // barA: joins prev tail (tail stores had tail-work time)

        // --- phase 1: own-K MFMAs (j=0..3) — operands produced locally last step
        f32x4 acc0 = (f32x4){0,0,0,0}, acc1 = (f32x4){0,0,0,0};
#pragma unroll
        for (int j = 0; j < 4; ++j) {
            bf16x8 a = *(const bf16x8*)&hread[rb][(abase + 32 * j) & 511];
            acc0 = __builtin_amdgcn_mfma_f32_16x16x32_bf16(a, wf0[j], acc0, 0, 0, 0);
            acc1 = __builtin_amdgcn_mfma_f32_16x16x32_bf16(a, wf1[j], acc1, 0, 0, 0);
        }

        // --- poll peers for h(t-1) (tag t), deposit hread(t)[peer] + hist
        if (t && wave != 0) {
            const unsigned want = (unsigned)t;
            u64 v0, v1;
            do {
                v0 = __hip_atomic_load(&mb_peer[lane * 2],     __ATOMIC_RELAXED, AGENT);
                v1 = __hip_atomic_load(&mb_peer[lane * 2 + 1], __ATOMIC_RELAXED, AGENT);
            } while ((unsigned)(v0 >> 32) != want || (unsigned)(v1 >> 32) != want);
            union { unsigned u; float f; } d0, d1;
            d0.u = (unsigned)v0; d1.u = (unsigned)v1;
            // hread(t)[peer] = k0*h(t-1) + k1*h(t-2) + k2*h(t-3) + k3*h(t-4)
            const float q0 = k1 * hist[rm2][j0]     + k2 * hist[rm3][j0]     + k3 * hist[rt][j0];
            const float q1 = k1 * hist[rm2][j0 + 1] + k2 * hist[rm3][j0 + 1] + k3 * hist[rt][j0 + 1];
            hread[rb][j0]     = (__bf16)(q0 + k0 * d0.f);
            hread[rb][j0 + 1] = (__bf16)(q1 + k0 * d1.f);
            hist[rm1][j0]     = d0.f;
            hist[rm1][j0 + 1] = d1.f;
        }
        __syncthreads();   // barB: poll loads consumed; queue ~empty

        // --- xp(t+1) prefetch (in flight through phase-2 + tanh of NEXT step)
        float nxA = 0.f, nxB = 0.f;
        if (comp) {
            nxA = stA[(size_t)(t + 1) * 512];
            nxB = stA[(size_t)(t + 1) * 512 + 16];
        }

        // --- Lagrange partial for own hread(t+1): k1 h(t-1)+k2 h(t-2)+k3 h(t-3)
        float ppA = 0.f, ppB = 0.f;
        if (comp) {
            ppA = k1 * hist[rm1][hA] + k2 * hist[rm2][hA] + k3 * hist[rm3][hA];
            ppB = k1 * hist[rm1][hB] + k2 * hist[rm2][hB] + k3 * hist[rm3][hB];
        }

        // --- phase 2: peer-K MFMAs (j=4..15), 4 fresh chains for ILP
        f32x4 c0a = (f32x4){0,0,0,0}, c0b = (f32x4){0,0,0,0};
        f32x4 c1a = (f32x4){0,0,0,0}, c1b = (f32x4){0,0,0,0};
#pragma unroll
        for (int j = 4; j < 10; ++j) {
            bf16x8 a = *(const bf16x8*)&hread[rb][(abase + 32 * j) & 511];
            c0a = __builtin_amdgcn_mfma_f32_16x16x32_bf16(a, wf0[j], c0a, 0, 0, 0);
            c1a = __builtin_amdgcn_mfma_f32_16x16x32_bf16(a, wf1[j], c1a, 0, 0, 0);
        }
#pragma unroll
        for (int j = 10; j < 16; ++j) {
            bf16x8 a = *(const bf16x8*)&hread[rb][(abase + 32 * j) & 511];
            c0b = __builtin_amdgcn_mfma_f32_16x16x32_bf16(a, wf0[j], c0b, 0, 0, 0);
            c1b = __builtin_amdgcn_mfma_f32_16x16x32_bf16(a, wf1[j], c1b, 0, 0, 0);
        }

        // --- tanh -> ship h(t) (tag t+1, parity wb) -> states -> own deposits
        if (comp) {
            const float hAv = fast_tanh(xA + acc0[0] + c0a[0] + c0b[0] + bA);
            const float hBv = fast_tanh(xB + acc1[0] + c1a[0] + c1b[0] + bB);
            u64* mb_self = mbox + (size_t)(((b << 1) | wb) * 4 + p) * 128;
            const u64 tag = (u64)(unsigned)(t + 1) << 32;
            union { float f; unsigned u; } cA, cB;
            cA.f = hAv; cB.f = hBv;
            __hip_atomic_store(&mb_self[wave * 32 + col],      tag | cA.u, __ATOMIC_RELAXED, AGENT);
            __hip_atomic_store(&mb_self[wave * 32 + col + 16], tag | cB.u, __ATOMIC_RELAXED, AGENT);
            stA[(size_t)t * 512]      = hAv;
            stA[(size_t)t * 512 + 16] = hBv;
            hist[rt][hA] = hAv;  hread[wb][hA] = (__bf16)(ppA + k0 * hAv);
            hist[rt][hB] = hBv;  hread[wb][hB] = (__bf16)(ppB + k0 * hBv);
        }
        xA = nxA; xB = nxB;
    }

    // final state output: each block writes its OWN slice of h(1023) (row 3)
    float* out2 = out + (size_t)32 * 1024 * 512 + (size_t)b * 512;
    if (comp) {
        out2[hA] = hist[3][hA];
        out2[hB] = hist[3][hB];
    }
}

// ---------------------------------------------------------------------------
extern "C" void kernel_launch(void* const* d_in, const int* in_sizes, int n_in,
                              void* d_out, int out_size, void* d_ws, size_t ws_size,
                              hipStream_t stream) {
    const float* x    = (const float*)d_in[0];   // [32,1024,512]
    const float* Wih  = (const float*)d_in[1];   // [512,512]
    const float* Whh  = (const float*)d_in[2];   // [512,512]
    const float* bih  = (const float*)d_in[3];   // [512]
    const float* bhh  = (const float*)d_in[4];   // [512]
    const float* kern = (const float*)d_in[5];   // [4]
    float* out = (float*)d_out;

    // mailboxes: 32 batches x 2 parity x 4 slices x 128 tagged u64 = 256 KB.
    // No init needed: exact tag match; 0xAAAAAAAA poison can't match.
    u64* mbox = (u64*)d_ws;

    dim3 g1(512, 8, 1);
    xproj_gemm_kernel<<<g1, 256, 0, stream>>>(x, Wih, bih, out);
    lagrange_rnn_kernel<<<128, 256, 0, stream>>>(Whh, bhh, kern, out, mbox);
}